// Round 3
// baseline (176.577 us; speedup 1.0000x reference)
//
#include <hip/hip_runtime.h>
#include <math.h>

#define H 2048
#define II 768
#define TT 512
#define EE 16

typedef float f32x4 __attribute__((ext_vector_type(4)));
typedef short s16x8 __attribute__((ext_vector_type(8)));
typedef unsigned short u16;
typedef u16 u16x4 __attribute__((ext_vector_type(4)));
typedef u16 u16x8 __attribute__((ext_vector_type(8)));

__device__ __forceinline__ u16 f2bf(float f) {
  unsigned int u = __float_as_uint(f);
  u += 0x7fffu + ((u >> 16) & 1u);   // round-to-nearest-even
  return (u16)(u >> 16);
}

// ---------------- router: logits, sigmoid, top2, counts ----------------
__global__ void router_kernel(const float* __restrict__ x, const float* __restrict__ gw,
                              int* __restrict__ counts, int* __restrict__ topi,
                              float* __restrict__ topw, int* __restrict__ pos) {
  int t = blockIdx.x;
  int tid = threadIdx.x;
  int wave = tid >> 6, lane = tid & 63;
  __shared__ float logits[EE];
  const float* xt = x + (size_t)t * H;
  for (int e = wave * 4; e < wave * 4 + 4; ++e) {
    const float* ge = gw + (size_t)e * H;
    float p = 0.f;
    for (int h = lane * 4; h < H; h += 64 * 4) {
      f32x4 xv = *(const f32x4*)(xt + h);
      f32x4 gv = *(const f32x4*)(ge + h);
      p += xv[0]*gv[0] + xv[1]*gv[1] + xv[2]*gv[2] + xv[3]*gv[3];
    }
    #pragma unroll
    for (int off = 32; off > 0; off >>= 1) p += __shfl_down(p, off);
    if (lane == 0) logits[e] = p;
  }
  __syncthreads();
  if (tid == 0) {
    float s[EE];
    #pragma unroll
    for (int e = 0; e < EE; ++e) s[e] = 1.f / (1.f + expf(-logits[e]));
    int i0 = 0;
    for (int e = 1; e < EE; ++e) if (s[e] > s[i0]) i0 = e;
    int i1 = -1;
    for (int e = 0; e < EE; ++e) {
      if (e == i0) continue;
      if (i1 < 0 || s[e] > s[i1]) i1 = e;
    }
    float w0 = s[i0], w1v = s[i1];
    float inv = 1.f / (w0 + w1v);
    w0 *= inv; w1v *= inv;
    topi[t*2+0] = i0; topi[t*2+1] = i1;
    topw[t*2+0] = w0; topw[t*2+1] = w1v;
    pos[t*2+0] = atomicAdd(&counts[i0], 1);
    pos[t*2+1] = atomicAdd(&counts[i1], 1);
  }
}

// ---------------- prefix sum over 16 experts ----------------
__global__ void prefix_kernel(const int* __restrict__ counts, int* __restrict__ base) {
  int s = 0;
  for (int e = 0; e < EE; ++e) { base[e] = s; s += counts[e]; }
  base[EE] = s;
}

// ---------------- gather tokens into expert-contiguous bf16 rows ----------------
__global__ void gather_kernel(const float* __restrict__ x, const int* __restrict__ topi,
                              const float* __restrict__ topw, const int* __restrict__ pos,
                              const int* __restrict__ base, u16* __restrict__ Xg,
                              int* __restrict__ tok_of, float* __restrict__ wt_of) {
  int t = blockIdx.x, slot = blockIdx.y;
  int e = topi[t*2 + slot];
  int row = base[e] + pos[t*2 + slot];
  if (threadIdx.x == 0) { tok_of[row] = t; wt_of[row] = topw[t*2 + slot]; }
  const float* xt = x + (size_t)t * H;
  u16* dst = Xg + (size_t)row * H;
  int h = threadIdx.x * 8;
  f32x4 v0 = *(const f32x4*)(xt + h);
  f32x4 v1 = *(const f32x4*)(xt + h + 4);
  u16x8 o;
  o[0]=f2bf(v0[0]); o[1]=f2bf(v0[1]); o[2]=f2bf(v0[2]); o[3]=f2bf(v0[3]);
  o[4]=f2bf(v1[0]); o[5]=f2bf(v1[1]); o[6]=f2bf(v1[2]); o[7]=f2bf(v1[3]);
  *(u16x8*)(dst + h) = o;
}

// ---------------- GEMM1: barrier-free, weight-resident-in-registers ----------------
// Block: 64 weight-rows (4 waves x 16n), K-chunk 512, one matrix (w1 or w3).
// Weights stream ONCE through the B-preload (deep load pipeline, no barriers);
// mt-loop streams L2-resident Xg fragments; fp32 partials to slab[mat][kc][1024][768].
__global__ __launch_bounds__(256, 2) void gemm1_kernel(
    const u16* __restrict__ Xg,
    const float* __restrict__ w1, const float* __restrict__ w1s,
    const float* __restrict__ w3, const float* __restrict__ w3s,
    const int* __restrict__ counts, const int* __restrict__ base,
    float* __restrict__ slab) {
  const int bx = blockIdx.x;           // 96 = nc(12) * kc(4) * mat(2)
  const int mat = bx & 1;
  const int kc  = (bx >> 1) & 3;
  const int nc  = bx >> 3;
  const int e = blockIdx.y;
  const int cnt = counts[e];
  if (cnt == 0) return;
  const int b0 = base[e];
  const int lane = threadIdx.x & 63;
  const int wv = threadIdx.x >> 6;
  const int n = nc * 64 + wv * 16 + (lane & 15);   // weight row 0..767
  const int k0 = kc * 512;
  const int klo = (lane >> 4) << 3;
  const float* W  = mat ? w3 : w1;
  const float* Ws = mat ? w3s : w1s;

  const f32x4 sc = *(const f32x4*)(Ws + ((size_t)e * II + n) * (H / 128) + kc * 4);
  const float* wp = W + ((size_t)e * II + n) * H + k0 + klo;
  s16x8 breg[16];
  #pragma unroll
  for (int s = 0; s < 16; ++s) {
    f32x4 v0 = *(const f32x4*)(wp + s * 32);
    f32x4 v1 = *(const f32x4*)(wp + s * 32 + 4);
    float ss = sc[s >> 2];
    u16x8 ob;
    ob[0]=f2bf(v0[0]*ss); ob[1]=f2bf(v0[1]*ss); ob[2]=f2bf(v0[2]*ss); ob[3]=f2bf(v0[3]*ss);
    ob[4]=f2bf(v1[0]*ss); ob[5]=f2bf(v1[1]*ss); ob[6]=f2bf(v1[2]*ss); ob[7]=f2bf(v1[3]*ss);
    breg[s] = __builtin_bit_cast(s16x8, ob);
  }

  float* out = slab + ((size_t)mat * 4 + kc) * ((size_t)1024 * II);
  for (int mt = 0; mt * 16 < cnt; ++mt) {
    const u16* ap = Xg + (size_t)(b0 + mt * 16 + (lane & 15)) * H + k0 + klo;
    f32x4 acc = {};
    #pragma unroll
    for (int s = 0; s < 16; ++s) {
      s16x8 a = *(const s16x8*)(ap + s * 32);
      acc = __builtin_amdgcn_mfma_f32_16x16x32_bf16(a, breg[s], acc, 0, 0, 0);
    }
    const int r0 = mt * 16 + ((lane >> 4) << 2);
    #pragma unroll
    for (int r = 0; r < 4; ++r) {
      if (r0 + r < cnt) out[(size_t)(b0 + r0 + r) * II + n] = acc[r];
    }
  }
}

// ---------------- silu combine: sum kc-chunks, silu(g)*u -> Ag bf16 ----------------
__global__ void silu_kernel(const float* __restrict__ slab, u16* __restrict__ Ag) {
  const size_t i = ((size_t)blockIdx.x * 256 + threadIdx.x) * 4;
  const float* G = slab;
  const float* U = slab + (size_t)4 * 1024 * II;
  f32x4 g = {}, u = {};
  #pragma unroll
  for (int kc = 0; kc < 4; ++kc) {
    g += *(const f32x4*)(G + (size_t)kc * 1024 * II + i);
    u += *(const f32x4*)(U + (size_t)kc * 1024 * II + i);
  }
  u16x4 o;
  #pragma unroll
  for (int j = 0; j < 4; ++j) {
    float a = g[j] / (1.f + expf(-g[j])) * u[j];
    o[j] = f2bf(a);
  }
  *(u16x4*)(Ag + i) = o;
}

// ---------------- GEMM2: barrier-free, w2-resident (full K=768) ----------------
__global__ __launch_bounds__(256, 2) void gemm2_kernel(
    const u16* __restrict__ Ag,
    const float* __restrict__ w2, const float* __restrict__ w2s,
    const int* __restrict__ counts, const int* __restrict__ base,
    const int* __restrict__ tok_of, const float* __restrict__ wt_of,
    float* __restrict__ y) {
  const int nc = blockIdx.x;           // 0..31
  const int e = blockIdx.y;
  const int cnt = counts[e];
  if (cnt == 0) return;
  const int b0 = base[e];
  const int lane = threadIdx.x & 63;
  const int wv = threadIdx.x >> 6;
  const int n = nc * 64 + wv * 16 + (lane & 15);   // output col 0..2047
  const int klo = (lane >> 4) << 3;

  const float* wp = w2 + ((size_t)e * H + n) * II + klo;
  const float* sp = w2s + ((size_t)e * H + n) * (II / 128);
  float scal[6];
  #pragma unroll
  for (int j = 0; j < 6; ++j) scal[j] = sp[j];
  s16x8 breg[24];
  #pragma unroll
  for (int s = 0; s < 24; ++s) {
    f32x4 v0 = *(const f32x4*)(wp + s * 32);
    f32x4 v1 = *(const f32x4*)(wp + s * 32 + 4);
    float ss = scal[s >> 2];
    u16x8 ob;
    ob[0]=f2bf(v0[0]*ss); ob[1]=f2bf(v0[1]*ss); ob[2]=f2bf(v0[2]*ss); ob[3]=f2bf(v0[3]*ss);
    ob[4]=f2bf(v1[0]*ss); ob[5]=f2bf(v1[1]*ss); ob[6]=f2bf(v1[2]*ss); ob[7]=f2bf(v1[3]*ss);
    breg[s] = __builtin_bit_cast(s16x8, ob);
  }

  for (int mt = 0; mt * 16 < cnt; ++mt) {
    const u16* ap = Ag + (size_t)(b0 + mt * 16 + (lane & 15)) * II + klo;
    f32x4 acc = {};
    #pragma unroll
    for (int s = 0; s < 24; ++s) {
      s16x8 a = *(const s16x8*)(ap + s * 32);
      acc = __builtin_amdgcn_mfma_f32_16x16x32_bf16(a, breg[s], acc, 0, 0, 0);
    }
    const int r0 = mt * 16 + ((lane >> 4) << 2);
    #pragma unroll
    for (int r = 0; r < 4; ++r) {
      const int mrow = r0 + r;
      if (mrow < cnt) {
        const int g = b0 + mrow;
        atomicAdd(y + (size_t)tok_of[g] * H + n, acc[r] * wt_of[g]);
      }
    }
  }
}

extern "C" void kernel_launch(void* const* d_in, const int* in_sizes, int n_in,
                              void* d_out, int out_size, void* d_ws, size_t ws_size,
                              hipStream_t stream) {
  const float* x   = (const float*)d_in[0];
  const float* gw  = (const float*)d_in[1];
  const float* w1  = (const float*)d_in[2];
  const float* w1s = (const float*)d_in[3];
  const float* w3  = (const float*)d_in[4];
  const float* w3s = (const float*)d_in[5];
  const float* w2  = (const float*)d_in[6];
  const float* w2s = (const float*)d_in[7];
  float* y = (float*)d_out;

  char* ws = (char*)d_ws;
  int*   counts = (int*)(ws + 0);            // 16 ints
  int*   basep  = (int*)(ws + 64);           // 17 ints
  int*   topi   = (int*)(ws + 256);          // 1024 ints
  float* topw   = (float*)(ws + 256 + 4096);
  int*   pos    = (int*)(ws + 256 + 8192);
  int*   tok_of = (int*)(ws + 256 + 12288);
  float* wt_of  = (float*)(ws + 256 + 16384);
  u16*   Xg     = (u16*)(ws + 20736);                     // 1152 x 2048 bf16 = 4718592 B
  u16*   Ag     = (u16*)(ws + 20736 + 4718592);           // 1152 x 768 bf16  = 1769472 B
  float* slab   = (float*)(ws + 20736 + 4718592 + 1769472); // [2][4][1024][768] f32 = 25165824 B

  hipMemsetAsync(counts, 0, 64, stream);
  hipMemsetAsync(y, 0, (size_t)out_size * sizeof(float), stream);

  router_kernel<<<TT, 256, 0, stream>>>(x, gw, counts, topi, topw, pos);
  prefix_kernel<<<1, 1, 0, stream>>>(counts, basep);
  gather_kernel<<<dim3(TT, 2), 256, 0, stream>>>(x, topi, topw, pos, basep, Xg, tok_of, wt_of);
  gemm1_kernel<<<dim3(96, EE), 256, 0, stream>>>(Xg, w1, w1s, w3, w3s, counts, basep, slab);
  silu_kernel<<<(1024 * II) / (256 * 4), 256, 0, stream>>>(slab, Ag);
  gemm2_kernel<<<dim3(H / 64, EE), 256, 0, stream>>>(Ag, w2, w2s, counts, basep, tok_of, wt_of, y);
}

// Round 4
// 139.643 us; speedup vs baseline: 1.2645x; 1.2645x over previous
//
#include <hip/hip_runtime.h>
#include <math.h>

#define H 2048
#define II 768
#define TT 512
#define EE 16
#define BK 64

typedef float f32x4 __attribute__((ext_vector_type(4)));
typedef short s16x8 __attribute__((ext_vector_type(8)));
typedef unsigned short u16;
typedef u16 u16x4 __attribute__((ext_vector_type(4)));
typedef u16 u16x8 __attribute__((ext_vector_type(8)));

__device__ __forceinline__ u16 f2bf(float f) {
  unsigned int u = __float_as_uint(f);
  u += 0x7fffu + ((u >> 16) & 1u);   // round-to-nearest-even
  return (u16)(u >> 16);
}

// ---------------- router: logits, sigmoid, top2, counts ----------------
__global__ void router_kernel(const float* __restrict__ x, const float* __restrict__ gw,
                              int* __restrict__ counts, int* __restrict__ topi,
                              float* __restrict__ topw, int* __restrict__ pos) {
  int t = blockIdx.x;
  int tid = threadIdx.x;
  int wave = tid >> 6, lane = tid & 63;
  __shared__ float logits[EE];
  const float* xt = x + (size_t)t * H;
  for (int e = wave * 4; e < wave * 4 + 4; ++e) {
    const float* ge = gw + (size_t)e * H;
    float p = 0.f;
    for (int h = lane * 4; h < H; h += 64 * 4) {
      f32x4 xv = *(const f32x4*)(xt + h);
      f32x4 gv = *(const f32x4*)(ge + h);
      p += xv[0]*gv[0] + xv[1]*gv[1] + xv[2]*gv[2] + xv[3]*gv[3];
    }
    #pragma unroll
    for (int off = 32; off > 0; off >>= 1) p += __shfl_down(p, off);
    if (lane == 0) logits[e] = p;
  }
  __syncthreads();
  if (tid == 0) {
    float s[EE];
    #pragma unroll
    for (int e = 0; e < EE; ++e) s[e] = 1.f / (1.f + expf(-logits[e]));
    int i0 = 0;
    for (int e = 1; e < EE; ++e) if (s[e] > s[i0]) i0 = e;
    int i1 = -1;
    for (int e = 0; e < EE; ++e) {
      if (e == i0) continue;
      if (i1 < 0 || s[e] > s[i1]) i1 = e;
    }
    float w0 = s[i0], w1v = s[i1];
    float inv = 1.f / (w0 + w1v);
    w0 *= inv; w1v *= inv;
    topi[t*2+0] = i0; topi[t*2+1] = i1;
    topw[t*2+0] = w0; topw[t*2+1] = w1v;
    pos[t*2+0] = atomicAdd(&counts[i0], 1);
    pos[t*2+1] = atomicAdd(&counts[i1], 1);
  }
}

// ---------------- prefix sum over 16 experts ----------------
__global__ void prefix_kernel(const int* __restrict__ counts, int* __restrict__ base) {
  int s = 0;
  for (int e = 0; e < EE; ++e) { base[e] = s; s += counts[e]; }
  base[EE] = s;
}

// ---------------- gather tokens into expert-contiguous bf16 rows ----------------
__global__ void gather_kernel(const float* __restrict__ x, const int* __restrict__ topi,
                              const float* __restrict__ topw, const int* __restrict__ pos,
                              const int* __restrict__ base, u16* __restrict__ Xg,
                              int* __restrict__ tok_of, float* __restrict__ wt_of) {
  int t = blockIdx.x, slot = blockIdx.y;
  int e = topi[t*2 + slot];
  int row = base[e] + pos[t*2 + slot];
  if (threadIdx.x == 0) { tok_of[row] = t; wt_of[row] = topw[t*2 + slot]; }
  const float* xt = x + (size_t)t * H;
  u16* dst = Xg + (size_t)row * H;
  int h = threadIdx.x * 8;
  f32x4 v0 = *(const f32x4*)(xt + h);
  f32x4 v1 = *(const f32x4*)(xt + h + 4);
  u16x8 o;
  o[0]=f2bf(v0[0]); o[1]=f2bf(v0[1]); o[2]=f2bf(v0[2]); o[3]=f2bf(v0[3]);
  o[4]=f2bf(v1[0]); o[5]=f2bf(v1[1]); o[6]=f2bf(v1[2]); o[7]=f2bf(v1[3]);
  *(u16x8*)(dst + h) = o;
}

// ---------------- GEMM1: split-K x4, 2-phase LDS pipeline -> fp32 partial slabs --------
// BM=64, BN=16, BK=64, K-chunk 512. grid (48*4, 16) = 3072 blocks, 8 resident/CU.
__global__ __launch_bounds__(256, 8) void gemm1_kernel(
    const u16* __restrict__ Xg,
    const float* __restrict__ w1, const float* __restrict__ w1s,
    const float* __restrict__ w3, const float* __restrict__ w3s,
    const int* __restrict__ counts, const int* __restrict__ base,
    float* __restrict__ slab) {
  const int bx = blockIdx.x;
  const int nc = bx >> 2, kc = bx & 3;
  const int e = blockIdx.y;
  const int cnt = counts[e];
  if (cnt == 0) return;
  const int n0 = nc * 16;
  const int k0 = kc * 512;
  const int b0 = base[e];
  const int tid = threadIdx.x;
  const int lane = tid & 63;
  const int w = tid >> 6;

  __shared__ __align__(16) u16 As[64 * 64];
  __shared__ __align__(16) u16 Bs[2][16 * 64];   // [0]=w1, [1]=w3

  // staging coords (reg-staged, XOR-swizzled both sides)
  const int rA = tid >> 3;                 // rows rA and rA+32
  const int cA = (tid & 7) << 3;
  const int cAs = cA ^ ((rA & 7) << 3);    // (rA+32)&7 == rA&7
  const int isB3 = tid >> 7;
  const int rB = (tid & 127) >> 3;         // 0..15
  const int cBs = cA ^ ((rB & 7) << 3);
  const float* wsrc = (isB3 ? w3 : w1) + (size_t)(e * II + n0 + rB) * H + k0 + cA;
  const float* ssrc = (isB3 ? w3s : w1s) + (size_t)(e * II + n0 + rB) * (H / 128) + kc * 4;
  u16* bdst = &Bs[isB3][rB * 64 + cBs];

  // compute coords
  const int arow = w * 16 + (lane & 15);
  const int acol0 = (lane >> 4) << 3;
  const int brow = lane & 15;
  const int aswz = (arow & 7) << 3;
  const int bswz = (brow & 7) << 3;

  float* outG = slab + ((size_t)kc) * ((size_t)1024 * II);
  float* outU = slab + ((size_t)(4 + kc)) * ((size_t)1024 * II);

  const int nmt = (cnt + 63) >> 6;
  for (int mt = 0; mt < nmt; ++mt) {
    const u16* asrc = Xg + (size_t)(b0 + mt * 64 + rA) * H + k0 + cA;
    f32x4 accg = {}, accu = {};
    s16x8 a0, a1; f32x4 bv0, bv1; float sc;
    // prologue: load+store tile 0
    a0 = *(const s16x8*)(asrc);
    a1 = *(const s16x8*)(asrc + (size_t)32 * H);
    bv0 = *(const f32x4*)(wsrc);
    bv1 = *(const f32x4*)(wsrc + 4);
    sc = ssrc[0];
    {
      *(s16x8*)(As + rA * 64 + cAs) = a0;
      *(s16x8*)(As + (rA + 32) * 64 + cAs) = a1;
      u16x8 ob;
      ob[0]=f2bf(bv0[0]*sc); ob[1]=f2bf(bv0[1]*sc); ob[2]=f2bf(bv0[2]*sc); ob[3]=f2bf(bv0[3]*sc);
      ob[4]=f2bf(bv1[0]*sc); ob[5]=f2bf(bv1[1]*sc); ob[6]=f2bf(bv1[2]*sc); ob[7]=f2bf(bv1[3]*sc);
      *(u16x8*)bdst = ob;
    }
    __syncthreads();
    for (int t = 0; t < 512 / BK; ++t) {
      const bool notlast = (t + 1 < 512 / BK);
      if (notlast) {   // issue next tile's loads BEFORE compute (T14)
        const int k1 = (t + 1) * BK;
        a0 = *(const s16x8*)(asrc + k1);
        a1 = *(const s16x8*)(asrc + (size_t)32 * H + k1);
        bv0 = *(const f32x4*)(wsrc + k1);
        bv1 = *(const f32x4*)(wsrc + k1 + 4);
        sc = ssrc[k1 >> 7];
      }
      #pragma unroll
      for (int ks = 0; ks < 2; ++ks) {
        const int ac = ks * 32 + acol0;
        s16x8 af  = *(const s16x8*)(As + arow * 64 + (ac ^ aswz));
        const int bix = brow * 64 + (ac ^ bswz);
        s16x8 b1f = *(const s16x8*)(Bs[0] + bix);
        s16x8 b3f = *(const s16x8*)(Bs[1] + bix);
        accg = __builtin_amdgcn_mfma_f32_16x16x32_bf16(af, b1f, accg, 0, 0, 0);
        accu = __builtin_amdgcn_mfma_f32_16x16x32_bf16(af, b3f, accu, 0, 0, 0);
      }
      __syncthreads();
      if (notlast) {
        *(s16x8*)(As + rA * 64 + cAs) = a0;
        *(s16x8*)(As + (rA + 32) * 64 + cAs) = a1;
        u16x8 ob;
        ob[0]=f2bf(bv0[0]*sc); ob[1]=f2bf(bv0[1]*sc); ob[2]=f2bf(bv0[2]*sc); ob[3]=f2bf(bv0[3]*sc);
        ob[4]=f2bf(bv1[0]*sc); ob[5]=f2bf(bv1[1]*sc); ob[6]=f2bf(bv1[2]*sc); ob[7]=f2bf(bv1[3]*sc);
        *(u16x8*)bdst = ob;
      }
      __syncthreads();
    }
    // epilogue: fp32 partials to slabs
    const int col = n0 + (lane & 15);
    #pragma unroll
    for (int r4 = 0; r4 < 4; ++r4) {
      int mrow = mt * 64 + w * 16 + ((lane >> 4) << 2) + r4;
      if (mrow < cnt) {
        outG[(size_t)(b0 + mrow) * II + col] = accg[r4];
        outU[(size_t)(b0 + mrow) * II + col] = accu[r4];
      }
    }
  }
}

// ---------------- silu combine: sum kc-chunks, silu(g)*u -> Ag bf16 ----------------
__global__ void silu_kernel(const float* __restrict__ slab, u16* __restrict__ Ag) {
  const size_t i = ((size_t)blockIdx.x * 256 + threadIdx.x) * 4;
  const float* G = slab;
  const float* U = slab + (size_t)4 * 1024 * II;
  f32x4 g = {}, u = {};
  #pragma unroll
  for (int kc = 0; kc < 4; ++kc) {
    g += *(const f32x4*)(G + (size_t)kc * 1024 * II + i);
    u += *(const f32x4*)(U + (size_t)kc * 1024 * II + i);
  }
  u16x4 o;
  #pragma unroll
  for (int j = 0; j < 4; ++j) {
    float a = g[j] / (1.f + expf(-g[j])) * u[j];
    o[j] = f2bf(a);
  }
  *(u16x4*)(Ag + i) = o;
}

// ---------------- GEMM2: split-K x2, 2-phase LDS pipeline -> atomicAdd y --------------
// BM=64, BN=32, BK=64, K-chunk 384. grid (64*2, 16) = 2048 blocks, 8 resident/CU.
__global__ __launch_bounds__(256, 8) void gemm2_kernel(
    const u16* __restrict__ Ag,
    const float* __restrict__ w2, const float* __restrict__ w2s,
    const int* __restrict__ counts, const int* __restrict__ base,
    const int* __restrict__ tok_of, const float* __restrict__ wt_of,
    float* __restrict__ y) {
  const int bx = blockIdx.x;
  const int nc = bx >> 1, kc = bx & 1;
  const int e = blockIdx.y;
  const int cnt = counts[e];
  if (cnt == 0) return;
  const int n0 = nc * 32;
  const int k0 = kc * 384;
  const int b0 = base[e];
  const int tid = threadIdx.x;
  const int lane = tid & 63;
  const int w = tid >> 6;

  __shared__ __align__(16) u16 As[64 * 64];
  __shared__ __align__(16) u16 Bs[32 * 64];

  const int rA = tid >> 3;                 // rows rA and rA+32
  const int cA = (tid & 7) << 3;
  const int cAs = cA ^ ((rA & 7) << 3);
  const int rB = tid >> 3;                 // 0..31
  const int cBs = cA ^ ((rB & 7) << 3);
  const float* wsrc = w2 + (size_t)(e * H + n0 + rB) * II + k0 + cA;
  const float* ssrc = w2s + (size_t)(e * H + n0 + rB) * (II / 128) + kc * 3;
  u16* bdst = &Bs[rB * 64 + cBs];

  const int arow = w * 16 + (lane & 15);
  const int acol0 = (lane >> 4) << 3;
  const int brow = lane & 15;
  const int aswz = (arow & 7) << 3;

  const int nmt = (cnt + 63) >> 6;
  for (int mt = 0; mt < nmt; ++mt) {
    const u16* asrc = Ag + (size_t)(b0 + mt * 64 + rA) * II + k0 + cA;
    f32x4 acc0 = {}, acc1 = {};
    s16x8 a0, a1; f32x4 bv0, bv1; float sc;
    a0 = *(const s16x8*)(asrc);
    a1 = *(const s16x8*)(asrc + (size_t)32 * II);
    bv0 = *(const f32x4*)(wsrc);
    bv1 = *(const f32x4*)(wsrc + 4);
    sc = ssrc[0];
    {
      *(s16x8*)(As + rA * 64 + cAs) = a0;
      *(s16x8*)(As + (rA + 32) * 64 + cAs) = a1;
      u16x8 ob;
      ob[0]=f2bf(bv0[0]*sc); ob[1]=f2bf(bv0[1]*sc); ob[2]=f2bf(bv0[2]*sc); ob[3]=f2bf(bv0[3]*sc);
      ob[4]=f2bf(bv1[0]*sc); ob[5]=f2bf(bv1[1]*sc); ob[6]=f2bf(bv1[2]*sc); ob[7]=f2bf(bv1[3]*sc);
      *(u16x8*)bdst = ob;
    }
    __syncthreads();
    for (int t = 0; t < 384 / BK; ++t) {
      const bool notlast = (t + 1 < 384 / BK);
      if (notlast) {
        const int k1 = (t + 1) * BK;
        a0 = *(const s16x8*)(asrc + k1);
        a1 = *(const s16x8*)(asrc + (size_t)32 * II + k1);
        bv0 = *(const f32x4*)(wsrc + k1);
        bv1 = *(const f32x4*)(wsrc + k1 + 4);
        sc = ssrc[k1 >> 7];
      }
      #pragma unroll
      for (int ks = 0; ks < 2; ++ks) {
        const int ac = ks * 32 + acol0;
        s16x8 af  = *(const s16x8*)(As + arow * 64 + (ac ^ aswz));
        s16x8 b0f = *(const s16x8*)(Bs + brow * 64 + (ac ^ ((brow & 7) << 3)));
        const int br1 = brow + 16;
        s16x8 b1f = *(const s16x8*)(Bs + br1 * 64 + (ac ^ ((br1 & 7) << 3)));
        acc0 = __builtin_amdgcn_mfma_f32_16x16x32_bf16(af, b0f, acc0, 0, 0, 0);
        acc1 = __builtin_amdgcn_mfma_f32_16x16x32_bf16(af, b1f, acc1, 0, 0, 0);
      }
      __syncthreads();
      if (notlast) {
        *(s16x8*)(As + rA * 64 + cAs) = a0;
        *(s16x8*)(As + (rA + 32) * 64 + cAs) = a1;
        u16x8 ob;
        ob[0]=f2bf(bv0[0]*sc); ob[1]=f2bf(bv0[1]*sc); ob[2]=f2bf(bv0[2]*sc); ob[3]=f2bf(bv0[3]*sc);
        ob[4]=f2bf(bv1[0]*sc); ob[5]=f2bf(bv1[1]*sc); ob[6]=f2bf(bv1[2]*sc); ob[7]=f2bf(bv1[3]*sc);
        *(u16x8*)bdst = ob;
      }
      __syncthreads();
    }
    // epilogue: scatter-add weighted output
    #pragma unroll
    for (int r4 = 0; r4 < 4; ++r4) {
      int mrow = mt * 64 + w * 16 + ((lane >> 4) << 2) + r4;
      if (mrow < cnt) {
        int grow = b0 + mrow;
        int t = tok_of[grow];
        float wt = wt_of[grow];
        atomicAdd(y + (size_t)t * H + n0 + (lane & 15), acc0[r4] * wt);
        atomicAdd(y + (size_t)t * H + n0 + 16 + (lane & 15), acc1[r4] * wt);
      }
    }
  }
}

extern "C" void kernel_launch(void* const* d_in, const int* in_sizes, int n_in,
                              void* d_out, int out_size, void* d_ws, size_t ws_size,
                              hipStream_t stream) {
  const float* x   = (const float*)d_in[0];
  const float* gw  = (const float*)d_in[1];
  const float* w1  = (const float*)d_in[2];
  const float* w1s = (const float*)d_in[3];
  const float* w3  = (const float*)d_in[4];
  const float* w3s = (const float*)d_in[5];
  const float* w2  = (const float*)d_in[6];
  const float* w2s = (const float*)d_in[7];
  float* y = (float*)d_out;

  char* ws = (char*)d_ws;
  int*   counts = (int*)(ws + 0);            // 16 ints
  int*   basep  = (int*)(ws + 64);           // 17 ints
  int*   topi   = (int*)(ws + 256);          // 1024 ints
  float* topw   = (float*)(ws + 256 + 4096);
  int*   pos    = (int*)(ws + 256 + 8192);
  int*   tok_of = (int*)(ws + 256 + 12288);
  float* wt_of  = (float*)(ws + 256 + 16384);
  u16*   Xg     = (u16*)(ws + 20736);                     // 1152 x 2048 bf16 = 4718592 B
  u16*   Ag     = (u16*)(ws + 20736 + 4718592);           // 1152 x 768 bf16  = 1769472 B
  float* slab   = (float*)(ws + 20736 + 4718592 + 1769472); // [2][4][1024][768] f32 = 25165824 B

  hipMemsetAsync(counts, 0, 64, stream);
  hipMemsetAsync(y, 0, (size_t)out_size * sizeof(float), stream);

  router_kernel<<<TT, 256, 0, stream>>>(x, gw, counts, topi, topw, pos);
  prefix_kernel<<<1, 1, 0, stream>>>(counts, basep);
  gather_kernel<<<dim3(TT, 2), 256, 0, stream>>>(x, topi, topw, pos, basep, Xg, tok_of, wt_of);
  gemm1_kernel<<<dim3(48 * 4, EE), 256, 0, stream>>>(Xg, w1, w1s, w3, w3s, counts, basep, slab);
  silu_kernel<<<(1024 * II) / (256 * 4), 256, 0, stream>>>(slab, Ag);
  gemm2_kernel<<<dim3(64 * 2, EE), 256, 0, stream>>>(Ag, w2, w2s, counts, basep, tok_of, wt_of, y);
}